// Round 3
// baseline (122.062 us; speedup 1.0000x reference)
//
#include <hip/hip_runtime.h>
#include <hip/hip_bf16.h>
#include <stdint.h>

#define LOG2E 1.4426950408889634f
#define LN2   0.6931471805599453f

typedef float f32x4 __attribute__((ext_vector_type(4)));
typedef short s16x8 __attribute__((ext_vector_type(8)));
typedef short s16x4 __attribute__((ext_vector_type(4)));
typedef uint32_t u32x4 __attribute__((ext_vector_type(4)));

__device__ inline float fexp2(float x) { return __builtin_amdgcn_exp2f(x); }
__device__ inline float frcp (float x) { return __builtin_amdgcn_rcpf(x); }
__device__ inline float flog2(float x) { return __builtin_amdgcn_logf(x); }
__device__ inline float ftanh(float x) {
  float e = fexp2(x * (2.0f * LOG2E));
  return 1.0f - 2.0f * frcp(e + 1.0f);
}
__device__ inline short f2bf(float x) {
  uint32_t u = __float_as_uint(x);
  uint32_t r = (u + 0x7fffu + ((u >> 16) & 1u)) >> 16;
  return (short)r;
}
__device__ inline float bf2f(short h) {
  return __uint_as_float(((uint32_t)(uint16_t)h) << 16);
}

// ---------------------------------------------------------------------------
// Kernel P: pack adjacency -> bitmask [8*1024 rows][32 u32 words]
// Self-detects whether adj is stored as int32 (bool promoted) or uint8.
// Probe reads stay within the first 8 MB (valid in both interpretations).
// ---------------------------------------------------------------------------
__global__ __launch_bounds__(256) void k_adjpack(
    const void* __restrict__ adj, uint32_t* __restrict__ bits)
{
  __shared__ uint32_t smode[4];
  const uint32_t* w32 = (const uint32_t*)adj;
  // probe: 256 words per block from the first 1 MB (words 0..262143)
  uint32_t probe = w32[blockIdx.x * 256 + threadIdx.x];
  uint32_t any = (probe > 1u) ? 1u : 0u;
  for (int m = 1; m < 64; m <<= 1) any |= __shfl_xor(any, m, 64);
  if ((threadIdx.x & 63) == 0) smode[threadIdx.x >> 6] = any;
  __syncthreads();
  uint32_t bytemode = smode[0] | smode[1] | smode[2] | smode[3];

  int gid = blockIdx.x * 256 + threadIdx.x;   // output dword, 32 edges
  uint32_t out = 0;
  if (bytemode) {
    const u32x4* a = (const u32x4*)((const uint8_t*)adj + (size_t)gid * 32);
    u32x4 q0 = a[0], q1 = a[1];
#pragma unroll
    for (int k = 0; k < 4; k++) {
      uint32_t w0 = q0[k], w1 = q1[k];
#pragma unroll
      for (int j = 0; j < 4; j++) {
        out |= (((w0 >> (8 * j)) & 0xffu) ? 1u : 0u) << (4 * k + j);
        out |= (((w1 >> (8 * j)) & 0xffu) ? 1u : 0u) << (16 + 4 * k + j);
      }
    }
  } else {
    const int* a32 = (const int*)adj + (size_t)gid * 32;
#pragma unroll
    for (int k = 0; k < 32; k += 4) {
      u32x4 q = *(const u32x4*)(a32 + k);
#pragma unroll
      for (int j = 0; j < 4; j++) out |= (q[j] ? 1u : 0u) << (k + j);
    }
  }
  bits[gid] = out;
}

// ---------------------------------------------------------------------------
// Kernel E: emb gather + concat -> xcb bf16 hi/lo planes [8192][128]
// ---------------------------------------------------------------------------
__global__ __launch_bounds__(256) void k_embcat(
    const float* __restrict__ x, const int* __restrict__ verts,
    const float* __restrict__ emb,
    short* __restrict__ xh, short* __restrict__ xl)
{
  int i = blockIdx.x * 256 + threadIdx.x;   // dword index (2 bf16 cols)
  if (i >= 8192 * 64) return;
  int row = i >> 6;
  int c2  = (i & 63) * 2;
  float v0, v1;
  if (c2 < 64) {
    v0 = x[row * 64 + c2];
    v1 = x[row * 64 + c2 + 1];
  } else {
    int v = verts[row];
    v0 = emb[(size_t)v * 64 + (c2 - 64)];
    v1 = emb[(size_t)v * 64 + (c2 - 64) + 1];
  }
  short h0 = f2bf(v0), h1 = f2bf(v1);
  short l0 = f2bf(v0 - bf2f(h0)), l1 = f2bf(v1 - bf2f(h1));
  ((uint32_t*)xh)[i] = (uint32_t)(uint16_t)h0 | ((uint32_t)(uint16_t)h1 << 16);
  ((uint32_t*)xl)[i] = (uint32_t)(uint16_t)l0 | ((uint32_t)(uint16_t)l1 << 16);
}

// ---------------------------------------------------------------------------
// Kernel H: h_prime = xc @ w[h]  (split-bf16 MFMA ~ fp32), tanh -> s,d
// hpb planes FRAGMENT-ARRANGED: [bh][mc(32)][ctl(CT)][lane(64)][8 bf16]
// ---------------------------------------------------------------------------
template<int FIN, int FO>
__global__ __launch_bounds__(256) void k_hprime(
    const short* __restrict__ xcbh, const short* __restrict__ xcbl,
    const float* __restrict__ w,
    const float* __restrict__ a_src, const float* __restrict__ a_dst,
    short* __restrict__ hpbh, short* __restrict__ hpbl,
    float* __restrict__ sp, float* __restrict__ dp)
{
  constexpr int CT  = FO / 16;
  constexpr int CTB = 8 * FO / 16;
  constexpr int CTW = CTB / 4;
  constexpr int KC  = FIN / 32;

  int blk = blockIdx.x;              // 512
  int b   = blk >> 6;
  int ntg = blk & 63;
  int tid = threadIdx.x;
  int w4  = tid >> 6;
  int l   = tid & 63;
  int l15 = l & 15, c = l >> 4;

  int row = ntg * 16 + l15;
  const short* arowh = xcbh + ((size_t)(b * 1024 + row)) * FIN;
  const short* arowl = xcbl + ((size_t)(b * 1024 + row)) * FIN;

  f32x4 acc[CTW];
#pragma unroll
  for (int i = 0; i < CTW; i++) acc[i] = (f32x4){0.f, 0.f, 0.f, 0.f};

  for (int kc = 0; kc < KC; ++kc) {
    s16x4 ah0 = *(const s16x4*)(arowh + kc * 32 + 4 * c);
    s16x4 ah1 = *(const s16x4*)(arowh + kc * 32 + 4 * c + 16);
    s16x4 al0 = *(const s16x4*)(arowl + kc * 32 + 4 * c);
    s16x4 al1 = *(const s16x4*)(arowl + kc * 32 + 4 * c + 16);
    s16x8 afh, afl;
#pragma unroll
    for (int j = 0; j < 4; j++) {
      afh[j] = ah0[j]; afh[4 + j] = ah1[j];
      afl[j] = al0[j]; afl[4 + j] = al1[j];
    }
#pragma unroll
    for (int i = 0; i < CTW; i++) {
      int ct  = w4 * CTW + i;
      int col = ct * 16 + l15;
      int h = col / FO, o = col % FO;
      const float* wp = w + (size_t)h * FIN * FO + o;
      s16x8 bfh, bfl;
#pragma unroll
      for (int j = 0; j < 8; j++) {
        int k = kc * 32 + 4 * c + (j & 3) + ((j >> 2) << 4);
        float wv = wp[(size_t)k * FO];
        short hh = f2bf(wv);
        bfh[j] = hh;
        bfl[j] = f2bf(wv - bf2f(hh));
      }
      acc[i] = __builtin_amdgcn_mfma_f32_16x16x32_bf16(afh, bfh, acc[i], 0, 0, 0);
      acc[i] = __builtin_amdgcn_mfma_f32_16x16x32_bf16(afl, bfh, acc[i], 0, 0, 0);
      acc[i] = __builtin_amdgcn_mfma_f32_16x16x32_bf16(afh, bfl, acc[i], 0, 0, 0);
    }
  }

  float s_acc[CTW][4];
  float d_acc[CTW][4];
#pragma unroll
  for (int i = 0; i < CTW; i++) {
    int ct  = w4 * CTW + i;
    int col = ct * 16 + l15;
    int h = col / FO, o = col % FO;
    float asv = a_src[h * FO + o];
    float adv = a_dst[h * FO + o];
    s16x4 hbh, hbl;
#pragma unroll
    for (int r = 0; r < 4; r++) {
      float hp = acc[i][r];
      short hh = f2bf(hp);
      hbh[r] = hh;
      hbl[r] = f2bf(hp - bf2f(hh));
      float t = ftanh(hp);
      s_acc[i][r] = t * asv;
      d_acc[i][r] = t * adv;
    }
    int bh  = b * 8 + h;
    int ctl = o >> 4;
    size_t off = ((((size_t)(bh * 32 + (ntg >> 1))) * CT + ctl) * 64 + l) * 16 + (size_t)(ntg & 1) * 8;
    *(s16x4*)((char*)hpbh + off) = hbh;
    *(s16x4*)((char*)hpbl + off) = hbl;
  }

  constexpr int HW = (CTW * 16) / FO;
#pragma unroll
  for (int hh = 0; hh < HW; ++hh) {
#pragma unroll
    for (int r = 0; r < 4; r++) {
      float sv = 0.f, dv = 0.f;
#pragma unroll
      for (int i = hh * CT; i < (hh + 1) * CT; ++i) { sv += s_acc[i][r]; dv += d_acc[i][r]; }
      for (int m = 1; m < 16; m <<= 1) {
        sv += __shfl_xor(sv, m, 64);
        dv += __shfl_xor(dv, m, 64);
      }
      if (l15 == 0) {
        int ct0 = w4 * CTW + hh * CT;
        int h   = (ct0 * 16) / FO;
        int bh  = b * 8 + h;
        int rn  = ntg * 16 + 4 * c + r;
        sp[bh * 1024 + rn] = sv * LOG2E;
        dp[bh * 1024 + rn] = dv * LOG2E;
      }
    }
  }
}

// ---------------------------------------------------------------------------
// Kernel A: masked softmax(leaky(s+d)) @ h_prime, split-bf16 PV, bitmask adj
// ---------------------------------------------------------------------------
template<int CT, bool IS_L0>
__global__ __launch_bounds__(256) void k_attn(
    const float* __restrict__ sp, const float* __restrict__ dp,
    const short* __restrict__ hpbh, const short* __restrict__ hpbl,
    const uint32_t* __restrict__ adjbits,
    const float* __restrict__ bias,
    void* __restrict__ outh, void* __restrict__ outl)
{
  __shared__ float dl[1024];
  __shared__ float red[4];

  int blk = blockIdx.x;          // 1024
  int bh  = blk >> 4;
  int rb  = (blk & 15) * 64;
  int b   = bh >> 3;
  int tid = threadIdx.x;
  int w4  = tid >> 6, l = tid & 63, l15 = l & 15, c = l >> 4;

  const float* dsrc = dp + bh * 1024;
  float mxl = -1e30f;
  for (int i = tid; i < 1024; i += 256) {
    float v = dsrc[i];
    dl[i] = v;
    mxl = fmaxf(mxl, v);
  }
  for (int m = 1; m < 64; m <<= 1) mxl = fmaxf(mxl, __shfl_xor(mxl, m, 64));
  if (l == 0) red[w4] = mxl;
  __syncthreads();
  float maxd = fmaxf(fmaxf(red[0], red[1]), fmaxf(red[2], red[3]));

  int n = rb + w4 * 16 + l15;
  float svn = sp[bh * 1024 + n];
  float su  = svn + maxd;
  float ub  = fmaxf(su, 0.2f * su);      // >= true row max (leaky monotone)
  const uint32_t* arow = adjbits + ((size_t)(b * 1024 + n)) * 32;
  const short* hpbaseh = hpbh + (size_t)bh * 32 * CT * 512;
  const short* hpbasel = hpbl + (size_t)bh * 32 * CT * 512;

  f32x4 acc[CT];
#pragma unroll
  for (int i = 0; i < CT; i++) acc[i] = (f32x4){0.f, 0.f, 0.f, 0.f};
  float psum = 0.f;

  for (int mc = 0; mc < 32; ++mc) {
    s16x8 bh_[CT], bl_[CT];
#pragma unroll
    for (int i = 0; i < CT; i++) {
      bh_[i] = *(const s16x8*)(hpbaseh + ((size_t)(mc * CT + i) * 64 + l) * 8);
      bl_[i] = *(const s16x8*)(hpbasel + ((size_t)(mc * CT + i) * 64 + l) * 8);
    }

    uint32_t bits = arow[mc];
    f32x4 d0 = *(const f32x4*)&dl[mc * 32 + 4 * c];
    f32x4 d1 = *(const f32x4*)&dl[mc * 32 + 16 + 4 * c];

    s16x8 pfh, pfl;
#pragma unroll
    for (int j = 0; j < 4; j++) {
      float sc = svn + d0[j];
      sc = fmaxf(sc, 0.2f * sc);
      float p = fexp2(sc - ub);
      p = ((bits >> (4 * c + j)) & 1u) ? p : 0.f;
      psum += p;
      short ph = f2bf(p);
      pfh[j] = ph;
      pfl[j] = f2bf(p - bf2f(ph));

      float sc2 = svn + d1[j];
      sc2 = fmaxf(sc2, 0.2f * sc2);
      float p2 = fexp2(sc2 - ub);
      p2 = ((bits >> (16 + 4 * c + j)) & 1u) ? p2 : 0.f;
      psum += p2;
      short p2h = f2bf(p2);
      pfh[4 + j] = p2h;
      pfl[4 + j] = f2bf(p2 - bf2f(p2h));
    }
#pragma unroll
    for (int i = 0; i < CT; i++) {
      acc[i] = __builtin_amdgcn_mfma_f32_16x16x32_bf16(pfh, bh_[i], acc[i], 0, 0, 0);
      acc[i] = __builtin_amdgcn_mfma_f32_16x16x32_bf16(pfl, bh_[i], acc[i], 0, 0, 0);
      acc[i] = __builtin_amdgcn_mfma_f32_16x16x32_bf16(pfh, bl_[i], acc[i], 0, 0, 0);
    }
  }

  psum += __shfl_xor(psum, 16, 64);
  psum += __shfl_xor(psum, 32, 64);

#pragma unroll
  for (int r = 0; r < 4; r++) {
    float rs  = __shfl(psum, 4 * c + r, 64);
    float inv = frcp(rs);
    int rown  = rb + w4 * 16 + 4 * c + r;
#pragma unroll
    for (int i = 0; i < CT; i++) {
      float v = acc[i][r] * inv;
      int col = i * 16 + l15;
      int h   = bh & 7;
      if (IS_L0) {
        v += bias[col];
        v = v > 0.f ? v : fexp2(v * LOG2E) - 1.f;   // elu
        size_t idx = ((size_t)(b * 1024 + rown)) * 256 + h * 32 + col;
        short vh = f2bf(v);
        ((short*)outh)[idx] = vh;
        ((short*)outl)[idx] = f2bf(v - bf2f(vh));
      } else {
        ((float*)outh)[(((size_t)(b * 8 + h)) * 1024 + rown) * 16 + col] = v;
      }
    }
  }
}

// ---------------------------------------------------------------------------
// Kernel F: mean over heads + bias + log_softmax(16)
// ---------------------------------------------------------------------------
__global__ __launch_bounds__(256) void k_final(
    const float* __restrict__ out1, const float* __restrict__ b1,
    float* __restrict__ out)
{
  int idx = blockIdx.x * 256 + threadIdx.x;
  if (idx >= 8192) return;
  int b = idx >> 10, n = idx & 1023;
  float v[16];
#pragma unroll
  for (int o = 0; o < 16; o++) v[o] = 0.f;
  for (int h = 0; h < 8; h++) {
    const float* p = out1 + (((size_t)(b * 8 + h)) * 1024 + n) * 16;
#pragma unroll
    for (int o = 0; o < 16; o++) v[o] += p[o];
  }
  float mx = -1e30f;
#pragma unroll
  for (int o = 0; o < 16; o++) {
    v[o] = v[o] * 0.125f + b1[o];
    mx = fmaxf(mx, v[o]);
  }
  float s = 0.f;
#pragma unroll
  for (int o = 0; o < 16; o++) s += fexp2((v[o] - mx) * LOG2E);
  float lse = flog2(s) * LN2;
#pragma unroll
  for (int o = 0; o < 16; o++) out[(size_t)idx * 16 + o] = v[o] - mx - lse;
}

// ---------------------------------------------------------------------------
extern "C" void kernel_launch(void* const* d_in, const int* in_sizes, int n_in,
                              void* d_out, int out_size, void* d_ws, size_t ws_size,
                              hipStream_t stream) {
  const float*   x     = (const float*)d_in[0];
  const int*     verts = (const int*)d_in[1];
  const void*    adj   = (const void*)d_in[2];   // int32 or uint8 — auto-detected
  const float*   emb   = (const float*)d_in[3];
  const float*   w0    = (const float*)d_in[4];
  const float*   as0   = (const float*)d_in[5];
  const float*   ad0   = (const float*)d_in[6];
  const float*   b0    = (const float*)d_in[7];
  const float*   w1    = (const float*)d_in[8];
  const float*   as1   = (const float*)d_in[9];
  const float*   ad1   = (const float*)d_in[10];
  const float*   b1    = (const float*)d_in[11];

  char* ws = (char*)d_ws;
  const size_t MB = 1ull << 20;
  short* xcbh  = (short*)(ws);                         // 2 MB
  short* xcbl  = (short*)(ws + 2 * MB);                // 2 MB
  short* hpb0h = (short*)(ws + 4 * MB);                // 4 MB
  short* hpb0l = (short*)(ws + 8 * MB);                // 4 MB
  float* s0    = (float*)(ws + 12 * MB);               // 256 KB
  float* d0    = (float*)(ws + 12 * MB + 256 * 1024);
  short* x1h   = (short*)(ws + 12 * MB + 512 * 1024);  // 4 MB
  short* x1l   = (short*)(ws + 16 * MB + 512 * 1024);  // 4 MB
  short* hpb1h = (short*)(ws + 20 * MB + 512 * 1024);  // 2 MB
  short* hpb1l = (short*)(ws + 22 * MB + 512 * 1024);  // 2 MB
  float* s1    = (float*)(ws + 24 * MB + 512 * 1024);  // 256 KB
  float* d1    = (float*)(ws + 24 * MB + 768 * 1024);
  float* out1  = (float*)(ws + 25 * MB);               // 4 MB
  uint32_t* adjbits = (uint32_t*)(ws + 29 * MB);       // 1 MB (ends 30 MB)
  float* out   = (float*)d_out;

  k_adjpack<<<1024, 256, 0, stream>>>(adj, adjbits);
  k_embcat<<<2048, 256, 0, stream>>>(x, verts, emb, xcbh, xcbl);
  k_hprime<128, 32><<<512, 256, 0, stream>>>(xcbh, xcbl, w0, as0, ad0, hpb0h, hpb0l, s0, d0);
  k_attn<2, true><<<1024, 256, 0, stream>>>(s0, d0, hpb0h, hpb0l, adjbits, b0, (void*)x1h, (void*)x1l);
  k_hprime<256, 16><<<512, 256, 0, stream>>>(x1h, x1l, w1, as1, ad1, hpb1h, hpb1l, s1, d1);
  k_attn<1, false><<<1024, 256, 0, stream>>>(s1, d1, hpb1h, hpb1l, adjbits, b1, (void*)out1, nullptr);
  k_final<<<32, 256, 0, stream>>>(out1, b1, out);
}

// Round 4
// 111.409 us; speedup vs baseline: 1.0956x; 1.0956x over previous
//
#include <hip/hip_runtime.h>
#include <hip/hip_bf16.h>
#include <stdint.h>

#define LOG2E 1.4426950408889634f
#define LN2   0.6931471805599453f

typedef float f32x4 __attribute__((ext_vector_type(4)));
typedef short s16x8 __attribute__((ext_vector_type(8)));
typedef short s16x4 __attribute__((ext_vector_type(4)));
typedef uint32_t u32x4 __attribute__((ext_vector_type(4)));

__device__ inline float fexp2(float x) { return __builtin_amdgcn_exp2f(x); }
__device__ inline float frcp (float x) { return __builtin_amdgcn_rcpf(x); }
__device__ inline float flog2(float x) { return __builtin_amdgcn_logf(x); }
__device__ inline float ftanh(float x) {
  float e = fexp2(x * (2.0f * LOG2E));
  return 1.0f - 2.0f * frcp(e + 1.0f);
}
__device__ inline short f2bf(float x) {
  uint32_t u = __float_as_uint(x);
  uint32_t r = (u + 0x7fffu + ((u >> 16) & 1u)) >> 16;
  return (short)r;
}
__device__ inline float bf2f(short h) {
  return __uint_as_float(((uint32_t)(uint16_t)h) << 16);
}
__device__ inline uint32_t pack2bf(float a, float b) {
  __hip_bfloat162 t = __float22bfloat162_rn(make_float2(a, b));
  uint32_t u; __builtin_memcpy(&u, &t, 4);
  return u;
}

// ---------------------------------------------------------------------------
// Kernel P: pack adjacency -> bitmask [8*1024 rows][32 u32 words]
// Self-detects whether adj is stored as int32 (bool promoted) or uint8.
// ---------------------------------------------------------------------------
__global__ __launch_bounds__(256) void k_adjpack(
    const void* __restrict__ adj, uint32_t* __restrict__ bits)
{
  __shared__ uint32_t smode[4];
  const uint32_t* w32 = (const uint32_t*)adj;
  uint32_t probe = w32[blockIdx.x * 256 + threadIdx.x];
  uint32_t any = (probe > 1u) ? 1u : 0u;
  for (int m = 1; m < 64; m <<= 1) any |= __shfl_xor(any, m, 64);
  if ((threadIdx.x & 63) == 0) smode[threadIdx.x >> 6] = any;
  __syncthreads();
  uint32_t bytemode = smode[0] | smode[1] | smode[2] | smode[3];

  int gid = blockIdx.x * 256 + threadIdx.x;
  uint32_t out = 0;
  if (bytemode) {
    const u32x4* a = (const u32x4*)((const uint8_t*)adj + (size_t)gid * 32);
    u32x4 q0 = a[0], q1 = a[1];
#pragma unroll
    for (int k = 0; k < 4; k++) {
      uint32_t w0 = q0[k], w1 = q1[k];
#pragma unroll
      for (int j = 0; j < 4; j++) {
        out |= (((w0 >> (8 * j)) & 0xffu) ? 1u : 0u) << (4 * k + j);
        out |= (((w1 >> (8 * j)) & 0xffu) ? 1u : 0u) << (16 + 4 * k + j);
      }
    }
  } else {
    const int* a32 = (const int*)adj + (size_t)gid * 32;
#pragma unroll
    for (int k = 0; k < 32; k += 4) {
      u32x4 q = *(const u32x4*)(a32 + k);
#pragma unroll
      for (int j = 0; j < 4; j++) out |= (q[j] ? 1u : 0u) << (k + j);
    }
  }
  bits[gid] = out;
}

// ---------------------------------------------------------------------------
// Kernel W: build fragment-arranged w hi/lo planes for both layers (once).
// wf[(ct*KC+kc)*64 + l][8]  with  k = kc*32 + 4c + (j&3) + ((j>>2)<<4)
// ---------------------------------------------------------------------------
__global__ __launch_bounds__(256) void k_wprep(
    const float* __restrict__ w0, const float* __restrict__ w1,
    short* __restrict__ wf0h, short* __restrict__ wf0l,
    short* __restrict__ wf1h, short* __restrict__ wf1l)
{
  int t = blockIdx.x * 256 + threadIdx.x;   // 0..8191
  int layer = t >> 12;
  int r = t & 4095;
  int l = r & 63, slot = r >> 6;
  int l15 = l & 15, c = l >> 4;
  int KC  = layer ? 8 : 4;
  int FO  = layer ? 16 : 32;
  int FIN = layer ? 256 : 128;
  int ct  = layer ? (slot >> 3) : (slot >> 2);
  int kc  = layer ? (slot & 7)  : (slot & 3);
  int col = ct * 16 + l15;
  int h   = layer ? (col >> 4) : (col >> 5);
  int o   = col & (FO - 1);
  const float* wp = (layer ? w1 : w0) + (size_t)h * FIN * FO + o;
  short* dh = (layer ? wf1h : wf0h) + (size_t)r * 8;
  short* dl = (layer ? wf1l : wf0l) + (size_t)r * 8;
#pragma unroll
  for (int j = 0; j < 8; j++) {
    int k = kc * 32 + 4 * c + (j & 3) + ((j >> 2) << 4);
    float wv = wp[(size_t)k * FO];
    short hh = f2bf(wv);
    dh[j] = hh;
    dl[j] = f2bf(wv - bf2f(hh));
  }
}

// ---------------------------------------------------------------------------
// Kernel E: emb gather + concat -> xcb bf16 hi/lo planes [8192][128]
// ---------------------------------------------------------------------------
__global__ __launch_bounds__(256) void k_embcat(
    const float* __restrict__ x, const int* __restrict__ verts,
    const float* __restrict__ emb,
    short* __restrict__ xh, short* __restrict__ xl)
{
  int i = blockIdx.x * 256 + threadIdx.x;
  if (i >= 8192 * 64) return;
  int row = i >> 6;
  int c2  = (i & 63) * 2;
  float v0, v1;
  if (c2 < 64) {
    v0 = x[row * 64 + c2];
    v1 = x[row * 64 + c2 + 1];
  } else {
    int v = verts[row];
    v0 = emb[(size_t)v * 64 + (c2 - 64)];
    v1 = emb[(size_t)v * 64 + (c2 - 64) + 1];
  }
  short h0 = f2bf(v0), h1 = f2bf(v1);
  short l0 = f2bf(v0 - bf2f(h0)), l1 = f2bf(v1 - bf2f(h1));
  ((uint32_t*)xh)[i] = (uint32_t)(uint16_t)h0 | ((uint32_t)(uint16_t)h1 << 16);
  ((uint32_t*)xl)[i] = (uint32_t)(uint16_t)l0 | ((uint32_t)(uint16_t)l1 << 16);
}

// ---------------------------------------------------------------------------
// Kernel H: h_prime = xc @ w[h]  (split-bf16, w frags preloaded), tanh -> s,d
// ---------------------------------------------------------------------------
template<int FIN, int FO>
__global__ __launch_bounds__(256) void k_hprime(
    const short* __restrict__ xcbh, const short* __restrict__ xcbl,
    const short* __restrict__ wfh, const short* __restrict__ wfl,
    const float* __restrict__ a_src, const float* __restrict__ a_dst,
    short* __restrict__ hpbh, short* __restrict__ hpbl,
    float* __restrict__ sp, float* __restrict__ dp)
{
  constexpr int CT  = FO / 16;
  constexpr int CTB = 8 * FO / 16;
  constexpr int CTW = CTB / 4;
  constexpr int KC  = FIN / 32;

  int blk = blockIdx.x;              // 512
  int b   = blk >> 6;
  int ntg = blk & 63;
  int tid = threadIdx.x;
  int w4  = tid >> 6;
  int l   = tid & 63;
  int l15 = l & 15, c = l >> 4;

  int row = ntg * 16 + l15;
  const short* arowh = xcbh + ((size_t)(b * 1024 + row)) * FIN;
  const short* arowl = xcbl + ((size_t)(b * 1024 + row)) * FIN;

  f32x4 acc[CTW];
#pragma unroll
  for (int i = 0; i < CTW; i++) acc[i] = (f32x4){0.f, 0.f, 0.f, 0.f};

  for (int kc = 0; kc < KC; ++kc) {
    s16x4 ah0 = *(const s16x4*)(arowh + kc * 32 + 4 * c);
    s16x4 ah1 = *(const s16x4*)(arowh + kc * 32 + 4 * c + 16);
    s16x4 al0 = *(const s16x4*)(arowl + kc * 32 + 4 * c);
    s16x4 al1 = *(const s16x4*)(arowl + kc * 32 + 4 * c + 16);
    s16x8 afh, afl;
#pragma unroll
    for (int j = 0; j < 4; j++) {
      afh[j] = ah0[j]; afh[4 + j] = ah1[j];
      afl[j] = al0[j]; afl[4 + j] = al1[j];
    }
#pragma unroll
    for (int i = 0; i < CTW; i++) {
      int ct = w4 * CTW + i;
      s16x8 bfh = *(const s16x8*)(wfh + ((size_t)(ct * KC + kc) * 64 + l) * 8);
      s16x8 bfl = *(const s16x8*)(wfl + ((size_t)(ct * KC + kc) * 64 + l) * 8);
      acc[i] = __builtin_amdgcn_mfma_f32_16x16x32_bf16(afh, bfh, acc[i], 0, 0, 0);
      acc[i] = __builtin_amdgcn_mfma_f32_16x16x32_bf16(afl, bfh, acc[i], 0, 0, 0);
      acc[i] = __builtin_amdgcn_mfma_f32_16x16x32_bf16(afh, bfl, acc[i], 0, 0, 0);
    }
  }

  float s_acc[CTW][4];
  float d_acc[CTW][4];
#pragma unroll
  for (int i = 0; i < CTW; i++) {
    int ct  = w4 * CTW + i;
    int col = ct * 16 + l15;
    int h = col / FO, o = col % FO;
    float asv = a_src[h * FO + o];
    float adv = a_dst[h * FO + o];
    s16x4 hbh, hbl;
#pragma unroll
    for (int r = 0; r < 4; r++) {
      float hp = acc[i][r];
      short hh = f2bf(hp);
      hbh[r] = hh;
      hbl[r] = f2bf(hp - bf2f(hh));
      float t = ftanh(hp);
      s_acc[i][r] = t * asv;
      d_acc[i][r] = t * adv;
    }
    int bh  = b * 8 + h;
    int ctl = o >> 4;
    size_t off = ((((size_t)(bh * 32 + (ntg >> 1))) * CT + ctl) * 64 + l) * 16 + (size_t)(ntg & 1) * 8;
    *(s16x4*)((char*)hpbh + off) = hbh;
    *(s16x4*)((char*)hpbl + off) = hbl;
  }

  constexpr int HW = (CTW * 16) / FO;
#pragma unroll
  for (int hh = 0; hh < HW; ++hh) {
#pragma unroll
    for (int r = 0; r < 4; r++) {
      float sv = 0.f, dv = 0.f;
#pragma unroll
      for (int i = hh * CT; i < (hh + 1) * CT; ++i) { sv += s_acc[i][r]; dv += d_acc[i][r]; }
      for (int m = 1; m < 16; m <<= 1) {
        sv += __shfl_xor(sv, m, 64);
        dv += __shfl_xor(dv, m, 64);
      }
      if (l15 == 0) {
        int ct0 = w4 * CTW + hh * CT;
        int h   = (ct0 * 16) / FO;
        int bh  = b * 8 + h;
        int rn  = ntg * 16 + 4 * c + r;
        sp[bh * 1024 + rn] = sv * LOG2E;
        dp[bh * 1024 + rn] = dv * LOG2E;
      }
    }
  }
}

// ---------------------------------------------------------------------------
// Kernel A: masked softmax(leaky(s+d)) @ h_prime
//   arg = max(A + d[m], B + 0.2 d[m]),  A = s-ub, B = 0.2s-ub  (per-lane consts)
//   P hi-plane only; h' hi+lo planes.
// ---------------------------------------------------------------------------
template<int CT, bool IS_L0>
__global__ __launch_bounds__(256) void k_attn(
    const float* __restrict__ sp, const float* __restrict__ dp,
    const short* __restrict__ hpbh, const short* __restrict__ hpbl,
    const uint32_t* __restrict__ adjbits,
    const float* __restrict__ bias,
    void* __restrict__ outh, void* __restrict__ outl)
{
  __shared__ float dl[1024];
  __shared__ float dl2[1024];
  __shared__ float red[4];

  int blk = blockIdx.x;          // 1024
  int bh  = blk >> 4;
  int rb  = (blk & 15) * 64;
  int b   = bh >> 3;
  int tid = threadIdx.x;
  int w4  = tid >> 6, l = tid & 63, l15 = l & 15, c = l >> 4;

  const float* dsrc = dp + bh * 1024;
  float mxl = -1e30f;
  for (int i = tid; i < 1024; i += 256) {
    float v = dsrc[i];
    dl[i] = v;
    dl2[i] = 0.2f * v;
    mxl = fmaxf(mxl, v);
  }
  for (int m = 1; m < 64; m <<= 1) mxl = fmaxf(mxl, __shfl_xor(mxl, m, 64));
  if (l == 0) red[w4] = mxl;
  __syncthreads();
  float maxd = fmaxf(fmaxf(red[0], red[1]), fmaxf(red[2], red[3]));

  int n = rb + w4 * 16 + l15;
  float svn = sp[bh * 1024 + n];
  float su  = svn + maxd;
  float ub  = fmaxf(su, 0.2f * su);      // >= true row max (leaky monotone)
  float A   = svn - ub;
  float B   = 0.2f * svn - ub;
  const uint32_t* arow = adjbits + ((size_t)(b * 1024 + n)) * 32;
  const short* hpbaseh = hpbh + (size_t)bh * 32 * CT * 512;
  const short* hpbasel = hpbl + (size_t)bh * 32 * CT * 512;

  f32x4 acc[CT];
#pragma unroll
  for (int i = 0; i < CT; i++) acc[i] = (f32x4){0.f, 0.f, 0.f, 0.f};
  float psA = 0.f, psB = 0.f;

  for (int mc = 0; mc < 32; ++mc) {
    s16x8 bh_[CT], bl_[CT];
#pragma unroll
    for (int i = 0; i < CT; i++) {
      bh_[i] = *(const s16x8*)(hpbaseh + ((size_t)(mc * CT + i) * 64 + l) * 8);
      bl_[i] = *(const s16x8*)(hpbasel + ((size_t)(mc * CT + i) * 64 + l) * 8);
    }

    uint32_t bits = arow[mc];
    uint32_t b0 = bits >> (4 * c);
    uint32_t b1 = bits >> (16 + 4 * c);
    f32x4 d0 = *(const f32x4*)&dl [mc * 32 + 4 * c];
    f32x4 e0 = *(const f32x4*)&dl2[mc * 32 + 4 * c];
    f32x4 d1 = *(const f32x4*)&dl [mc * 32 + 16 + 4 * c];
    f32x4 e1 = *(const f32x4*)&dl2[mc * 32 + 16 + 4 * c];

    float p[8];
#pragma unroll
    for (int j = 0; j < 4; j++) {
      float arg = fmaxf(A + d0[j], B + e0[j]);
      float pv  = fexp2(arg) * (float)((b0 >> j) & 1u);
      psA += pv;
      p[j] = pv;
      float arg2 = fmaxf(A + d1[j], B + e1[j]);
      float pv2  = fexp2(arg2) * (float)((b1 >> j) & 1u);
      psB += pv2;
      p[4 + j] = pv2;
    }
    union { s16x8 s; uint32_t w[4]; } pu;
    pu.w[0] = pack2bf(p[0], p[1]);
    pu.w[1] = pack2bf(p[2], p[3]);
    pu.w[2] = pack2bf(p[4], p[5]);
    pu.w[3] = pack2bf(p[6], p[7]);
#pragma unroll
    for (int i = 0; i < CT; i++) {
      acc[i] = __builtin_amdgcn_mfma_f32_16x16x32_bf16(pu.s, bh_[i], acc[i], 0, 0, 0);
      acc[i] = __builtin_amdgcn_mfma_f32_16x16x32_bf16(pu.s, bl_[i], acc[i], 0, 0, 0);
    }
  }

  float psum = psA + psB;
  psum += __shfl_xor(psum, 16, 64);
  psum += __shfl_xor(psum, 32, 64);

#pragma unroll
  for (int r = 0; r < 4; r++) {
    float rs  = __shfl(psum, 4 * c + r, 64);
    float inv = frcp(rs);
    int rown  = rb + w4 * 16 + 4 * c + r;
#pragma unroll
    for (int i = 0; i < CT; i++) {
      float v = acc[i][r] * inv;
      int col = i * 16 + l15;
      int h   = bh & 7;
      if (IS_L0) {
        v += bias[col];
        v = v > 0.f ? v : fexp2(v * LOG2E) - 1.f;   // elu
        size_t idx = ((size_t)(b * 1024 + rown)) * 256 + h * 32 + col;
        short vh = f2bf(v);
        ((short*)outh)[idx] = vh;
        ((short*)outl)[idx] = f2bf(v - bf2f(vh));
      } else {
        ((float*)outh)[(((size_t)(b * 8 + h)) * 1024 + rown) * 16 + col] = v;
      }
    }
  }
}

// ---------------------------------------------------------------------------
// Kernel F: mean over heads + bias + log_softmax(16)
// ---------------------------------------------------------------------------
__global__ __launch_bounds__(256) void k_final(
    const float* __restrict__ out1, const float* __restrict__ b1,
    float* __restrict__ out)
{
  int idx = blockIdx.x * 256 + threadIdx.x;
  if (idx >= 8192) return;
  int b = idx >> 10, n = idx & 1023;
  float v[16];
#pragma unroll
  for (int o = 0; o < 16; o++) v[o] = 0.f;
  for (int h = 0; h < 8; h++) {
    const float* p = out1 + (((size_t)(b * 8 + h)) * 1024 + n) * 16;
#pragma unroll
    for (int o = 0; o < 16; o++) v[o] += p[o];
  }
  float mx = -1e30f;
#pragma unroll
  for (int o = 0; o < 16; o++) {
    v[o] = v[o] * 0.125f + b1[o];
    mx = fmaxf(mx, v[o]);
  }
  float s = 0.f;
#pragma unroll
  for (int o = 0; o < 16; o++) s += fexp2((v[o] - mx) * LOG2E);
  float lse = flog2(s) * LN2;
#pragma unroll
  for (int o = 0; o < 16; o++) out[(size_t)idx * 16 + o] = v[o] - mx - lse;
}

// ---------------------------------------------------------------------------
extern "C" void kernel_launch(void* const* d_in, const int* in_sizes, int n_in,
                              void* d_out, int out_size, void* d_ws, size_t ws_size,
                              hipStream_t stream) {
  const float*   x     = (const float*)d_in[0];
  const int*     verts = (const int*)d_in[1];
  const void*    adj   = (const void*)d_in[2];   // int32 or uint8 — auto-detected
  const float*   emb   = (const float*)d_in[3];
  const float*   w0    = (const float*)d_in[4];
  const float*   as0   = (const float*)d_in[5];
  const float*   ad0   = (const float*)d_in[6];
  const float*   b0    = (const float*)d_in[7];
  const float*   w1    = (const float*)d_in[8];
  const float*   as1   = (const float*)d_in[9];
  const float*   ad1   = (const float*)d_in[10];
  const float*   b1    = (const float*)d_in[11];

  char* ws = (char*)d_ws;
  const size_t MB = 1ull << 20;
  short* xcbh  = (short*)(ws);                         // 2 MB
  short* xcbl  = (short*)(ws + 2 * MB);                // 2 MB
  short* hpb0h = (short*)(ws + 4 * MB);                // 4 MB
  short* hpb0l = (short*)(ws + 8 * MB);                // 4 MB
  float* s0    = (float*)(ws + 12 * MB);               // 256 KB
  float* d0    = (float*)(ws + 12 * MB + 256 * 1024);
  short* x1h   = (short*)(ws + 12 * MB + 512 * 1024);  // 4 MB
  short* x1l   = (short*)(ws + 16 * MB + 512 * 1024);  // 4 MB
  short* hpb1h = (short*)(ws + 20 * MB + 512 * 1024);  // 2 MB
  short* hpb1l = (short*)(ws + 22 * MB + 512 * 1024);  // 2 MB
  float* s1    = (float*)(ws + 24 * MB + 512 * 1024);  // 256 KB
  float* d1    = (float*)(ws + 24 * MB + 768 * 1024);
  float* out1  = (float*)(ws + 25 * MB);               // 4 MB
  uint32_t* adjbits = (uint32_t*)(ws + 29 * MB);       // 1 MB
  short* wf0h  = (short*)(ws + 30 * MB);               // 64 KB each
  short* wf0l  = (short*)(ws + 30 * MB + 64 * 1024);
  short* wf1h  = (short*)(ws + 30 * MB + 128 * 1024);
  short* wf1l  = (short*)(ws + 30 * MB + 192 * 1024);  // ends 30.25 MB
  float* out   = (float*)d_out;

  k_adjpack<<<1024, 256, 0, stream>>>(adj, adjbits);
  k_wprep<<<32, 256, 0, stream>>>(w0, w1, wf0h, wf0l, wf1h, wf1l);
  k_embcat<<<2048, 256, 0, stream>>>(x, verts, emb, xcbh, xcbl);
  k_hprime<128, 32><<<512, 256, 0, stream>>>(xcbh, xcbl, wf0h, wf0l, as0, ad0, hpb0h, hpb0l, s0, d0);
  k_attn<2, true><<<1024, 256, 0, stream>>>(s0, d0, hpb0h, hpb0l, adjbits, b0, (void*)x1h, (void*)x1l);
  k_hprime<256, 16><<<512, 256, 0, stream>>>(x1h, x1l, wf1h, wf1l, as1, ad1, hpb1h, hpb1l, s1, d1);
  k_attn<1, false><<<1024, 256, 0, stream>>>(s1, d1, hpb1h, hpb1l, adjbits, b1, (void*)out1, nullptr);
  k_final<<<32, 256, 0, stream>>>(out1, b1, out);
}